// Round 1
// baseline (69.715 us; speedup 1.0000x reference)
//
#include <hip/hip_runtime.h>
#include <hip/hip_bf16.h>

// Problem constants (match the reference's trie layout)
#define V_SZ   32768          // vocab
#define C_CH   32             // children per unigram
#define G_SZ   V_SZ           // unigram log-prob count
#define U_OFF  (V_SZ + 1)     // first bigram node index
#define K_SZ   (V_SZ * C_CH)  // bigram node count
#define X_SZ   (K_SZ + 1)     // pointers length
#define B_SZ   32             // batch
#define CHUNK  1024           // V-elements per block
#define NCHUNK (V_SZ / CHUNK) // 32 blocks along V per batch row

// One block per (batch b, V-chunk). 256 threads, 4 fp32 per thread (float4).
// Phase 1: coalesced fill out[b, v] = backoff[h_b] + logs[v].
// Phase 2 (after barrier): lanes 0..31 check the 32 children of h_b; if a
// child's token falls inside THIS block's chunk, overwrite with the bigram lp.
// Each override address is written (default then override) by the same block,
// so the __syncthreads (s_waitcnt vmcnt(0) + s_barrier) orders the two stores.
__global__ __launch_bounds__(256) void lookup_lm_kernel(
    const int* __restrict__ hist,      // (S, B)
    const int* __restrict__ idx_p,     // scalar
    const int* __restrict__ pointers,  // (X)
    const int* __restrict__ ids,       // (K)
    const float* __restrict__ logs,    // (L = 2X + G)
    float* __restrict__ out)           // (B, V)
{
    const int b     = blockIdx.y;
    const int chunk = blockIdx.x;
    const int s     = idx_p[0];

    const int h   = hist[(s - 1) * B_SZ + b];       // last context token (uniform/block)
    const int off = pointers[h];
    const int nc  = pointers[h + 1] - off + 1;      // num children
    const int first = h + off;                      // first child node id
    const float backoff = logs[X_SZ + G_SZ + h];    // unigram backoff weight

    // ---- Phase 1: dense backoff fill (coalesced float4) ----
    const int v0 = chunk * CHUNK + threadIdx.x * 4;
    float4 lg = *reinterpret_cast<const float4*>(logs + v0);
    float4 o;
    o.x = backoff + lg.x;
    o.y = backoff + lg.y;
    o.z = backoff + lg.z;
    o.w = backoff + lg.w;
    *reinterpret_cast<float4*>(out + b * V_SZ + v0) = o;

    __syncthreads();   // drains vmcnt before s_barrier -> fill visible before override

    // ---- Phase 2: sparse bigram override ----
    const int j = threadIdx.x;
    if (j < C_CH && j < nc) {
        const int node = first + j;
        const int tok  = ids[node - U_OFF];
        const int lo   = chunk * CHUNK;
        if (tok >= lo && tok < lo + CHUNK) {
            out[b * V_SZ + tok] = logs[node];
        }
    }
}

extern "C" void kernel_launch(void* const* d_in, const int* in_sizes, int n_in,
                              void* d_out, int out_size, void* d_ws, size_t ws_size,
                              hipStream_t stream) {
    const int*   hist     = (const int*)d_in[0];
    const int*   idx_p    = (const int*)d_in[1];
    const int*   pointers = (const int*)d_in[2];
    const int*   ids      = (const int*)d_in[3];
    const float* logs     = (const float*)d_in[4];
    float*       out      = (float*)d_out;

    dim3 grid(NCHUNK, B_SZ);   // 32 x 32 = 1024 blocks
    dim3 block(256);
    lookup_lm_kernel<<<grid, block, 0, stream>>>(hist, idx_p, pointers, ids, logs, out);
}